// Round 5
// baseline (440.324 us; speedup 1.0000x reference)
//
#include <hip/hip_runtime.h>
#include <hip/hip_bf16.h>

// Problem constants (B=64, T=2048, D=512, U=512)
#define BB 64
#define TT 2048
#define DD 512
#define UU 512
#define MM (BB * TT)                 // 131072 rows
#define CTX_ELEMS (BB * DD)          // context region of d_out
#define ATTN_OFF  CTX_ELEMS          // attention region offset in d_out

typedef __bf16 bf16x8 __attribute__((ext_vector_type(8)));
typedef float  f32x4  __attribute__((ext_vector_type(4)));
typedef unsigned short u16x8 __attribute__((ext_vector_type(8)));
typedef unsigned int u32;

#define GLOBAL_AS __attribute__((address_space(1)))
#define LDS_AS    __attribute__((address_space(3)))

__device__ __forceinline__ unsigned short f2bf(float f) {
    union { float f; unsigned u; } x; x.f = f;
    unsigned r = x.u + 0x7fffu + ((x.u >> 16) & 1u);   // RNE
    return (unsigned short)(r >> 16);
}

__device__ __forceinline__ float tanh_fast(float x) {
    x = fminf(fmaxf(x, -10.f), 10.f);                  // avoid inf*0
    float e = __builtin_amdgcn_exp2f(x * 2.885390082f); // e^(2x)
    return (e - 1.0f) * __builtin_amdgcn_rcpf(e + 1.0f);
}

// ---------------------------------------------------------------------------
// Kernel 1: W1 [D][U] f32 -> W1T bf16, tiled layout:
//   tile ti = (nt*16 + kt), nt = u>>7, kt = d>>5  (8 KB per tile)
//   within tile: [kc(4)][n(128)][e(8)] : kc = (d&31)>>3, n = u&127, e = d&7
// For a given nt (gy), the 16 kt-tiles are a CONTIGUOUS 128 KB slab.
// ---------------------------------------------------------------------------
__global__ void k_w1t(const float* __restrict__ W1, unsigned short* __restrict__ W1T) {
    int gid = blockIdx.x * 256 + threadIdx.x;   // 32768 threads
    int u  = gid & 511;
    int dc = gid >> 9;                          // d-chunk of 8, 0..63
    int d0 = dc * 8;
    u16x8 pk;
    #pragma unroll
    for (int e = 0; e < 8; ++e)
        pk[e] = f2bf(W1[(size_t)(d0 + e) * UU + u]);
    int nt = u >> 7, n = u & 127;
    int kt = dc >> 2, kc = dc & 3;
    size_t off = ((size_t)(nt * 16 + kt) * 8192 + kc * 2048 + n * 16) / 2;
    *(u16x8*)(W1T + off) = pk;
}

// ---------------------------------------------------------------------------
// Kernel 2: phc[b][u] = b1[u] + b2[u] + hidden[b,:] @ W2[:,u]
// ---------------------------------------------------------------------------
__global__ void k_phc(const float* __restrict__ hidden, const float* __restrict__ W2,
                      const float* __restrict__ b1, const float* __restrict__ b2,
                      float* __restrict__ phc) {
    const int b = blockIdx.x;
    const int u = threadIdx.x;         // 512 threads
    const float* h = hidden + (size_t)b * DD;
    float acc = b1[u] + b2[u];
    #pragma unroll 8
    for (int d = 0; d < DD; ++d)
        acc += h[d] * W2[(size_t)d * UU + u];
    phc[(size_t)b * UU + u] = acc;
}

// ---------------------------------------------------------------------------
// Kernel 3: partial-score GEMM, B-resident / barrier-free main loop.
// grid 256 = (b 0..63) x (gy 0..3), XCD-mapped: bid = (b&7) + 8*(gy + 4*(b>>3))
// so the 4 gy-siblings of a batch live on one XCD (feat L2 reuse).
// Block: 512 threads = 8 waves (4M x 2N). B slab (K=512 x N=128, 128 KB bf16)
// resident in LDS for the whole block; A fragments stream global->reg with a
// 3-set (2-deep) prefetch ladder; f32->bf16 convert in-reg. NO barriers in
// the K-loop. Block loops 8 m-tiles of BM=256 (= one full batch b).
// ---------------------------------------------------------------------------
__launch_bounds__(512, 1)
__global__ void k_score(const float* __restrict__ feat,
                        const unsigned short* __restrict__ W1T,
                        const float* __restrict__ phc,
                        const float* __restrict__ V,
                        float* __restrict__ part) {
    __shared__ __align__(16) unsigned short sB[16 * 4096];  // 128 KB
    __shared__ float sRed[8][64];

    const int tid  = threadIdx.x;
    const int lane = tid & 63;
    const int w    = tid >> 6;                // wave 0..7
    const int wm   = w >> 1, wc = w & 1;      // 4M x 2N

    const int bid = blockIdx.x;
    const int b   = (bid & 7) + 8 * (bid >> 5);
    const int gy  = (bid >> 3) & 3;

    // ---- fill B slab (once) ----
    const char* bslab = (const char*)W1T + (size_t)gy * 131072;
    #pragma unroll
    for (int p = 0; p < 16; ++p) {
        const char* src = bslab + (size_t)(p * 512 + tid) * 16;
        char* dst = (char*)sB + (size_t)(p * 512 + (tid & ~63)) * 16;
        __builtin_amdgcn_global_load_lds((const GLOBAL_AS u32*)src, (LDS_AS u32*)dst, 16, 0, 0);
    }
    // per-block constants (overlap with fill)
    float pc[4], vv[4];
    #pragma unroll
    for (int ns = 0; ns < 4; ++ns) {
        int ug = gy * 128 + wc * 64 + ns * 16 + (lane & 15);
        pc[ns] = phc[(size_t)b * UU + ug];
        vv[ns] = V[ug];
    }
    __syncthreads();   // B resident from here on; no more barriers in K-loop

    const int kcl   = lane >> 4;              // k-chunk of this lane
    const int rlane = lane & 15;              // row-in-frag / col-in-frag
    // A base addresses for m-tile 0 (bytes); row = b*2048 + mt*256 + wm*64 + ms*16 + rlane
    const char* fb0 = (const char*)feat +
        ((size_t)(b * TT) + wm * 64 + rlane) * 2048 + kcl * 32;

    // 3-set A register ladder (sets S0,S1,S2), each: 4 m-frags x 2 f32x4
    f32x4 s0_[8], s1_[8], s2_[8];

#define LOADA(S, ab0_, ab1_, ab2_, ab3_, kt_) do {                    \
    S[0] = *(const f32x4*)((ab0_) + (kt_) * 128);                     \
    S[1] = *(const f32x4*)((ab0_) + (kt_) * 128 + 16);                \
    S[2] = *(const f32x4*)((ab1_) + (kt_) * 128);                     \
    S[3] = *(const f32x4*)((ab1_) + (kt_) * 128 + 16);                \
    S[4] = *(const f32x4*)((ab2_) + (kt_) * 128);                     \
    S[5] = *(const f32x4*)((ab2_) + (kt_) * 128 + 16);                \
    S[6] = *(const f32x4*)((ab3_) + (kt_) * 128);                     \
    S[7] = *(const f32x4*)((ab3_) + (kt_) * 128 + 16); } while (0)

#define KSTEP(kt_, CUR) do {                                          \
    bf16x8 bfr[4];                                                    \
    _Pragma("unroll")                                                 \
    for (int ns_ = 0; ns_ < 4; ++ns_)                                 \
        bfr[ns_] = *(const bf16x8*)((const char*)sB + (kt_) * 8192 +  \
                    kcl * 2048 + (wc * 64 + ns_ * 16 + rlane) * 16);  \
    _Pragma("unroll")                                                 \
    for (int ms_ = 0; ms_ < 4; ++ms_) {                               \
        bf16x8 af_;                                                   \
        _Pragma("unroll")                                             \
        for (int j_ = 0; j_ < 4; ++j_) {                              \
            af_[j_]     = (__bf16)CUR[2 * ms_][j_];                   \
            af_[4 + j_] = (__bf16)CUR[2 * ms_ + 1][j_];               \
        }                                                             \
        _Pragma("unroll")                                             \
        for (int ns_ = 0; ns_ < 4; ++ns_)                             \
            acc[ms_][ns_] = __builtin_amdgcn_mfma_f32_16x16x32_bf16(  \
                af_, bfr[ns_], acc[ms_][ns_], 0, 0, 0);               \
    } } while (0)

    // prologue for mt=0
    {
        const char* a0 = fb0;
        const char* a1 = fb0 + 16 * 2048;
        const char* a2 = fb0 + 32 * 2048;
        const char* a3 = fb0 + 48 * 2048;
        LOADA(s0_, a0, a1, a2, a3, 0);
        LOADA(s1_, a0, a1, a2, a3, 1);
    }

    for (int mt = 0; mt < 8; ++mt) {
        const char* a0 = fb0 + (size_t)mt * 256 * 2048;
        const char* a1 = a0 + 16 * 2048;
        const char* a2 = a0 + 32 * 2048;
        const char* a3 = a0 + 48 * 2048;

        f32x4 acc[4][4];
        #pragma unroll
        for (int i = 0; i < 4; ++i)
            #pragma unroll
            for (int j = 0; j < 4; ++j)
                acc[i][j] = (f32x4){0.f, 0.f, 0.f, 0.f};

        // 16-step ladder, 3-set rotation, prefetch depth 2
        KSTEP(0,  s0_); LOADA(s2_, a0, a1, a2, a3, 2);
        KSTEP(1,  s1_); LOADA(s0_, a0, a1, a2, a3, 3);
        KSTEP(2,  s2_); LOADA(s1_, a0, a1, a2, a3, 4);
        KSTEP(3,  s0_); LOADA(s2_, a0, a1, a2, a3, 5);
        KSTEP(4,  s1_); LOADA(s0_, a0, a1, a2, a3, 6);
        KSTEP(5,  s2_); LOADA(s1_, a0, a1, a2, a3, 7);
        KSTEP(6,  s0_); LOADA(s2_, a0, a1, a2, a3, 8);
        KSTEP(7,  s1_); LOADA(s0_, a0, a1, a2, a3, 9);
        KSTEP(8,  s2_); LOADA(s1_, a0, a1, a2, a3, 10);
        KSTEP(9,  s0_); LOADA(s2_, a0, a1, a2, a3, 11);
        KSTEP(10, s1_); LOADA(s0_, a0, a1, a2, a3, 12);
        KSTEP(11, s2_); LOADA(s1_, a0, a1, a2, a3, 13);
        KSTEP(12, s0_); LOADA(s2_, a0, a1, a2, a3, 14);
        KSTEP(13, s1_); LOADA(s0_, a0, a1, a2, a3, 15);
        KSTEP(14, s2_);
        // prefetch next m-tile's kt=0,1 (hides under epilogue)
        if (mt < 7) {
            const char* n0 = a0 + 256 * 2048;
            const char* n1 = n0 + 16 * 2048;
            const char* n2 = n0 + 32 * 2048;
            const char* n3 = n0 + 48 * 2048;
            KSTEP(15, s0_);
            LOADA(s1_, n0, n1, n2, n3, 0);   // next tile kt=0 -> s1_? no: rotate
            LOADA(s2_, n0, n1, n2, n3, 1);
            // rename so next iteration's ladder starts at s0_: swap roles
            #pragma unroll
            for (int q = 0; q < 8; ++q) { s0_[q] = s1_[q]; s1_[q] = s2_[q]; }
        } else {
            KSTEP(15, s0_);
        }

        // --- epilogue: partial score over this block's 128 n-cols ---
        float pr[4][4];
        #pragma unroll
        for (int ms = 0; ms < 4; ++ms)
            #pragma unroll
            for (int rg = 0; rg < 4; ++rg) {
                float s = 0.f;
                #pragma unroll
                for (int ns = 0; ns < 4; ++ns)
                    s += tanh_fast(acc[ms][ns][rg] + pc[ns]) * vv[ns];
                pr[ms][rg] = s;
            }
        #pragma unroll
        for (int off = 1; off < 16; off <<= 1)
            #pragma unroll
            for (int ms = 0; ms < 4; ++ms)
                #pragma unroll
                for (int rg = 0; rg < 4; ++rg)
                    pr[ms][rg] += __shfl_xor(pr[ms][rg], off, 64);
        if ((lane & 15) == 0) {
            int rowg = lane >> 4;
            #pragma unroll
            for (int ms = 0; ms < 4; ++ms)
                #pragma unroll
                for (int rg = 0; rg < 4; ++rg)
                    sRed[w][ms * 16 + rowg * 4 + rg] = pr[ms][rg];
        }
        __syncthreads();
        if (tid < 256) {
            int wmx = tid >> 6, r = tid & 63;
            float v = sRed[2 * wmx][r] + sRed[2 * wmx + 1][r];
            part[(size_t)gy * MM + (size_t)b * TT + mt * 256 + tid] = v;
        }
        __syncthreads();   // sRed safe for next m-tile
    }
#undef KSTEP
#undef LOADA
}

// ---------------------------------------------------------------------------
// Kernel 4: sum 4 partials -> softmax over T -> d_out attn region.
// ---------------------------------------------------------------------------
__global__ void k_softmax(const float* __restrict__ part, float* __restrict__ dout) {
    const int b = blockIdx.x, tid = threadIdx.x;   // 256 threads
    float* sc = dout + ATTN_OFF + (size_t)b * TT;
    float v[8];
    float mx = -3.4e38f;
    #pragma unroll
    for (int i = 0; i < 8; ++i) {
        int t = tid + 256 * i;
        size_t idx = (size_t)b * TT + t;
        v[i] = part[idx] + part[MM + idx] + part[2 * MM + idx] + part[3 * MM + idx];
        mx = fmaxf(mx, v[i]);
    }
    __shared__ float red[256];
    red[tid] = mx; __syncthreads();
    for (int s = 128; s >= 1; s >>= 1) {
        if (tid < s) red[tid] = fmaxf(red[tid], red[tid + s]);
        __syncthreads();
    }
    mx = red[0]; __syncthreads();
    float sum = 0.f;
    #pragma unroll
    for (int i = 0; i < 8; ++i) { v[i] = __expf(v[i] - mx); sum += v[i]; }
    red[tid] = sum; __syncthreads();
    for (int s = 128; s >= 1; s >>= 1) {
        if (tid < s) red[tid] += red[tid + s];
        __syncthreads();
    }
    float inv = 1.0f / red[0];
    #pragma unroll
    for (int i = 0; i < 8; ++i) sc[tid + 256 * i] = v[i] * inv;
}

// ---------------------------------------------------------------------------
// Kernel 5: context[b][d] = sum_t w[b][t] * feat[b][t][d]
// grid (64, 8); 256 threads = 16 d-quads (float4) x 16 t-subgroups.
// ---------------------------------------------------------------------------
__global__ void k_context(const float* __restrict__ feat, float* __restrict__ dout) {
    const int b = blockIdx.x, dc = blockIdx.y;
    const int dq = threadIdx.x & 15;          // float4 lane
    const int ty = threadIdx.x >> 4;          // 0..15
    const int d = dc * 64 + dq * 4;
    const float* wgt = dout + ATTN_OFF + (size_t)b * TT;
    const float* f = feat + (size_t)b * TT * DD + d;
    float4 acc = {0.f, 0.f, 0.f, 0.f};
    #pragma unroll 4
    for (int i = 0; i < TT / 16; ++i) {
        int t = i * 16 + ty;
        float wv = wgt[t];
        float4 fv = *(const float4*)(f + (size_t)t * DD);
        acc.x += wv * fv.x; acc.y += wv * fv.y;
        acc.z += wv * fv.z; acc.w += wv * fv.w;
    }
    __shared__ float4 red[16][16];
    red[ty][dq] = acc; __syncthreads();
    if (ty == 0) {
        float4 s = red[0][dq];
        #pragma unroll
        for (int k = 1; k < 16; ++k) {
            float4 r = red[k][dq];
            s.x += r.x; s.y += r.y; s.z += r.z; s.w += r.w;
        }
        *(float4*)(dout + (size_t)b * DD + d) = s;
    }
}

// ---------------------------------------------------------------------------
extern "C" void kernel_launch(void* const* d_in, const int* in_sizes, int n_in,
                              void* d_out, int out_size, void* d_ws, size_t ws_size,
                              hipStream_t stream) {
    (void)in_sizes; (void)n_in; (void)out_size; (void)ws_size;
    const float* feat   = (const float*)d_in[0];
    const float* hidden = (const float*)d_in[1];
    const float* W1     = (const float*)d_in[2];
    const float* b1     = (const float*)d_in[3];
    const float* W2     = (const float*)d_in[4];
    const float* b2     = (const float*)d_in[5];
    const float* V      = (const float*)d_in[6];
    // d_in[7] = bV : softmax-invariant constant, unused.

    // ws layout: [0,512K) W1T bf16; [512K,640K) phc f32; [640K,640K+2M) partials
    unsigned short* W1T = (unsigned short*)d_ws;
    float* phc  = (float*)((char*)d_ws + 512 * 1024);
    float* part = (float*)((char*)d_ws + 640 * 1024);
    float* out  = (float*)d_out;

    hipLaunchKernelGGL(k_w1t,     dim3(128),    dim3(256), 0, stream, W1, W1T);
    hipLaunchKernelGGL(k_phc,     dim3(64),     dim3(512), 0, stream, hidden, W2, b1, b2, phc);
    hipLaunchKernelGGL(k_score,   dim3(256),    dim3(512), 0, stream, feat, W1T, phc, V, part);
    hipLaunchKernelGGL(k_softmax, dim3(64),     dim3(256), 0, stream, part, out);
    hipLaunchKernelGGL(k_context, dim3(64, 8),  dim3(256), 0, stream, feat, out);
}

// Round 6
// 326.685 us; speedup vs baseline: 1.3479x; 1.3479x over previous
//
#include <hip/hip_runtime.h>
#include <hip/hip_bf16.h>

// Problem constants (B=64, T=2048, D=512, U=512)
#define BB 64
#define TT 2048
#define DD 512
#define UU 512
#define MM (BB * TT)                 // 131072 rows
#define CTX_ELEMS (BB * DD)          // context region of d_out
#define ATTN_OFF  CTX_ELEMS          // attention region offset in d_out

typedef __bf16 bf16x8 __attribute__((ext_vector_type(8)));
typedef float  f32x4  __attribute__((ext_vector_type(4)));
typedef unsigned short u16x8 __attribute__((ext_vector_type(8)));
typedef unsigned int u32;

#define GLOBAL_AS __attribute__((address_space(1)))
#define LDS_AS    __attribute__((address_space(3)))

__device__ __forceinline__ unsigned short f2bf(float f) {
    union { float f; unsigned u; } x; x.f = f;
    unsigned r = x.u + 0x7fffu + ((x.u >> 16) & 1u);   // RNE
    return (unsigned short)(r >> 16);
}

__device__ __forceinline__ float tanh_fast(float x) {
    x = fminf(fmaxf(x, -10.f), 10.f);                  // avoid inf*0
    float e = __builtin_amdgcn_exp2f(x * 2.885390082f); // e^(2x)
    return (e - 1.0f) * __builtin_amdgcn_rcpf(e + 1.0f);
}

// ---------------------------------------------------------------------------
// Kernel 1: W1 [D][U] f32 -> W1T bf16, tiled layout:
//   tile ti = (nt*16 + kt), nt = u>>7, kt = d>>5  (8 KB per tile)
//   within tile: [kc(4)][n(128)][e(8)] : kc = (d&31)>>3, n = u&127, e = d&7
// For a given nt (gy), the 16 kt-tiles are a CONTIGUOUS 128 KB slab.
// ---------------------------------------------------------------------------
__global__ void k_w1t(const float* __restrict__ W1, unsigned short* __restrict__ W1T) {
    int gid = blockIdx.x * 256 + threadIdx.x;   // 32768 threads
    int u  = gid & 511;
    int dc = gid >> 9;                          // d-chunk of 8, 0..63
    int d0 = dc * 8;
    u16x8 pk;
    #pragma unroll
    for (int e = 0; e < 8; ++e)
        pk[e] = f2bf(W1[(size_t)(d0 + e) * UU + u]);
    int nt = u >> 7, n = u & 127;
    int kt = dc >> 2, kc = dc & 3;
    size_t off = ((size_t)(nt * 16 + kt) * 8192 + kc * 2048 + n * 16) / 2;
    *(u16x8*)(W1T + off) = pk;
}

// ---------------------------------------------------------------------------
// Kernel 2: phc[b][u] = b1[u] + b2[u] + hidden[b,:] @ W2[:,u]
// ---------------------------------------------------------------------------
__global__ void k_phc(const float* __restrict__ hidden, const float* __restrict__ W2,
                      const float* __restrict__ b1, const float* __restrict__ b2,
                      float* __restrict__ phc) {
    const int b = blockIdx.x;
    const int u = threadIdx.x;         // 512 threads
    const float* h = hidden + (size_t)b * DD;
    float acc = b1[u] + b2[u];
    #pragma unroll 8
    for (int d = 0; d < DD; ++d)
        acc += h[d] * W2[(size_t)d * UU + u];
    phc[(size_t)b * UU + u] = acc;
}

// ---------------------------------------------------------------------------
// Kernel 3: partial-score GEMM, B-resident / barrier-free K-loop.
// grid 256 = (b, gy), XCD-mapped: bid = (b&7) + 8*(gy + 4*(b>>3)) so the 4
// gy-siblings of a batch share an XCD (feat L2 reuse, verified R5: FETCH=1x).
// Block: 512 threads = 8 waves (4M x 2N), __launch_bounds__(512,2) -> 256
// VGPR cap (R5 spilled at the default 128). B slab (512K x 128N bf16, 128 KB)
// LDS-resident for the whole block. A streams global->reg (f32) with a
// period-2 ladder: step kt = { load f32(kt+2); cvt f32(kt+1)->bf16; mfma(kt) }.
// Register audit: acc 64 + fS0/fS1 64 + frA/frB 32 + temps ~30 = ~190 < 256.
// ---------------------------------------------------------------------------
__launch_bounds__(512, 2)
__global__ void k_score(const float* __restrict__ feat,
                        const unsigned short* __restrict__ W1T,
                        const float* __restrict__ phc,
                        const float* __restrict__ V,
                        float* __restrict__ part) {
    __shared__ __align__(16) unsigned short sB[16 * 4096];  // 128 KB
    __shared__ float sRed[8][64];

    const int tid  = threadIdx.x;
    const int lane = tid & 63;
    const int w    = tid >> 6;                // wave 0..7
    const int wm   = w >> 1, wc = w & 1;      // 4M x 2N

    const int bid = blockIdx.x;
    const int b   = (bid & 7) + 8 * (bid >> 5);
    const int gy  = (bid >> 3) & 3;

    // ---- fill B slab (once) ----
    const char* bslab = (const char*)W1T + (size_t)gy * 131072;
    #pragma unroll
    for (int p = 0; p < 16; ++p) {
        const char* src = bslab + (size_t)(p * 512 + tid) * 16;
        char* dst = (char*)sB + (size_t)(p * 512 + (tid & ~63)) * 16;
        __builtin_amdgcn_global_load_lds((const GLOBAL_AS u32*)src, (LDS_AS u32*)dst, 16, 0, 0);
    }
    // per-block constants (overlap with fill)
    float pc[4], vv[4];
    #pragma unroll
    for (int ns = 0; ns < 4; ++ns) {
        int ug = gy * 128 + wc * 64 + ns * 16 + (lane & 15);
        pc[ns] = phc[(size_t)b * UU + ug];
        vv[ns] = V[ug];
    }

    const int kcl   = lane >> 4;              // k-chunk of this lane (0..3)
    const int rlane = lane & 15;              // row-in-frag / col-in-frag
    // A base (bytes): row = b*2048 + wm*64 + rlane ; col-chunk = kcl*8 floats
    const char* fb0 = (const char*)feat +
        ((size_t)(b * TT) + wm * 64 + rlane) * 2048 + kcl * 32;

    f32x4  fS0[8], fS1[8];     // two f32 staging sets (4 m-frags x 8 floats)
    bf16x8 frA[4], frB[4];     // two bf16 fragment sets

#define LOADA(S, base_, kt_) do {                                         \
    S[0] = *(const f32x4*)((base_) + (kt_) * 128);                        \
    S[1] = *(const f32x4*)((base_) + (kt_) * 128 + 16);                   \
    S[2] = *(const f32x4*)((base_) + 16 * 2048 + (kt_) * 128);            \
    S[3] = *(const f32x4*)((base_) + 16 * 2048 + (kt_) * 128 + 16);       \
    S[4] = *(const f32x4*)((base_) + 32 * 2048 + (kt_) * 128);            \
    S[5] = *(const f32x4*)((base_) + 32 * 2048 + (kt_) * 128 + 16);       \
    S[6] = *(const f32x4*)((base_) + 48 * 2048 + (kt_) * 128);            \
    S[7] = *(const f32x4*)((base_) + 48 * 2048 + (kt_) * 128 + 16); } while (0)

#define CVT(FR, S) do {                                                   \
    _Pragma("unroll")                                                     \
    for (int f_ = 0; f_ < 4; ++f_) {                                      \
        _Pragma("unroll")                                                 \
        for (int j_ = 0; j_ < 4; ++j_) {                                  \
            FR[f_][j_]     = (__bf16)S[2 * f_][j_];                       \
            FR[f_][4 + j_] = (__bf16)S[2 * f_ + 1][j_];                   \
        } } } while (0)

#define KSTEP(kt_, FR) do {                                               \
    __builtin_amdgcn_s_setprio(1);                                        \
    _Pragma("unroll")                                                     \
    for (int ns_ = 0; ns_ < 4; ++ns_) {                                   \
        bf16x8 bfr_ = *(const bf16x8*)((const char*)sB + (kt_) * 8192 +   \
                      kcl * 2048 + (wc * 64 + ns_ * 16 + rlane) * 16);    \
        _Pragma("unroll")                                                 \
        for (int ms_ = 0; ms_ < 4; ++ms_)                                 \
            acc[ms_][ns_] = __builtin_amdgcn_mfma_f32_16x16x32_bf16(      \
                FR[ms_], bfr_, acc[ms_][ns_], 0, 0, 0);                   \
    }                                                                     \
    __builtin_amdgcn_s_setprio(0); } while (0)

    // prologue: A(kt0), A(kt1) of m-tile 0 in flight during B-fill
    LOADA(fS0, fb0, 0);
    LOADA(fS1, fb0, 1);
    __syncthreads();   // B resident from here; K-loop has NO barriers

    for (int mt = 0; mt < 8; ++mt) {
        const char* ab = fb0 + (size_t)mt * (256 * 2048);
        const char* nb = ab + ((mt < 7) ? 256 * 2048 : 0);

        f32x4 acc[4][4];
        #pragma unroll
        for (int i = 0; i < 4; ++i)
            #pragma unroll
            for (int j = 0; j < 4; ++j)
                acc[i][j] = (f32x4){0.f, 0.f, 0.f, 0.f};

        CVT(frA, fS0);                                   // kt0
        LOADA(fS0, ab, 2);  CVT(frB, fS1); KSTEP(0, frA);
        LOADA(fS1, ab, 3);  CVT(frA, fS0); KSTEP(1, frB);
        LOADA(fS0, ab, 4);  CVT(frB, fS1); KSTEP(2, frA);
        LOADA(fS1, ab, 5);  CVT(frA, fS0); KSTEP(3, frB);
        LOADA(fS0, ab, 6);  CVT(frB, fS1); KSTEP(4, frA);
        LOADA(fS1, ab, 7);  CVT(frA, fS0); KSTEP(5, frB);
        LOADA(fS0, ab, 8);  CVT(frB, fS1); KSTEP(6, frA);
        LOADA(fS1, ab, 9);  CVT(frA, fS0); KSTEP(7, frB);
        LOADA(fS0, ab, 10); CVT(frB, fS1); KSTEP(8, frA);
        LOADA(fS1, ab, 11); CVT(frA, fS0); KSTEP(9, frB);
        LOADA(fS0, ab, 12); CVT(frB, fS1); KSTEP(10, frA);
        LOADA(fS1, ab, 13); CVT(frA, fS0); KSTEP(11, frB);
        LOADA(fS0, ab, 14); CVT(frB, fS1); KSTEP(12, frA);
        LOADA(fS1, ab, 15); CVT(frA, fS0); KSTEP(13, frB);
        LOADA(fS0, nb, 0);  CVT(frB, fS1); KSTEP(14, frA);  // prefetch next tile kt0
        LOADA(fS1, nb, 1);                 KSTEP(15, frB);  // prefetch next tile kt1

        // --- epilogue: partial score over this block's 128 n-cols ---
        float pr[4][4];
        #pragma unroll
        for (int ms = 0; ms < 4; ++ms)
            #pragma unroll
            for (int rg = 0; rg < 4; ++rg) {
                float s = 0.f;
                #pragma unroll
                for (int ns = 0; ns < 4; ++ns)
                    s += tanh_fast(acc[ms][ns][rg] + pc[ns]) * vv[ns];
                pr[ms][rg] = s;
            }
        #pragma unroll
        for (int off = 1; off < 16; off <<= 1)
            #pragma unroll
            for (int ms = 0; ms < 4; ++ms)
                #pragma unroll
                for (int rg = 0; rg < 4; ++rg)
                    pr[ms][rg] += __shfl_xor(pr[ms][rg], off, 64);
        if ((lane & 15) == 0) {
            int rowg = lane >> 4;
            #pragma unroll
            for (int ms = 0; ms < 4; ++ms)
                #pragma unroll
                for (int rg = 0; rg < 4; ++rg)
                    sRed[w][ms * 16 + rowg * 4 + rg] = pr[ms][rg];
        }
        __syncthreads();
        if (tid < 256) {
            int wmx = tid >> 6, r = tid & 63;
            float v = sRed[2 * wmx][r] + sRed[2 * wmx + 1][r];
            part[(size_t)gy * MM + (size_t)b * TT + mt * 256 + tid] = v;
        }
        __syncthreads();   // sRed safe for next m-tile
    }
#undef KSTEP
#undef CVT
#undef LOADA
}

// ---------------------------------------------------------------------------
// Kernel 4: sum 4 partials -> softmax over T -> d_out attn region.
// ---------------------------------------------------------------------------
__global__ void k_softmax(const float* __restrict__ part, float* __restrict__ dout) {
    const int b = blockIdx.x, tid = threadIdx.x;   // 256 threads
    float* sc = dout + ATTN_OFF + (size_t)b * TT;
    float v[8];
    float mx = -3.4e38f;
    #pragma unroll
    for (int i = 0; i < 8; ++i) {
        int t = tid + 256 * i;
        size_t idx = (size_t)b * TT + t;
        v[i] = part[idx] + part[MM + idx] + part[2 * MM + idx] + part[3 * MM + idx];
        mx = fmaxf(mx, v[i]);
    }
    __shared__ float red[256];
    red[tid] = mx; __syncthreads();
    for (int s = 128; s >= 1; s >>= 1) {
        if (tid < s) red[tid] = fmaxf(red[tid], red[tid + s]);
        __syncthreads();
    }
    mx = red[0]; __syncthreads();
    float sum = 0.f;
    #pragma unroll
    for (int i = 0; i < 8; ++i) { v[i] = __expf(v[i] - mx); sum += v[i]; }
    red[tid] = sum; __syncthreads();
    for (int s = 128; s >= 1; s >>= 1) {
        if (tid < s) red[tid] += red[tid + s];
        __syncthreads();
    }
    float inv = 1.0f / red[0];
    #pragma unroll
    for (int i = 0; i < 8; ++i) sc[tid + 256 * i] = v[i] * inv;
}

// ---------------------------------------------------------------------------
// Kernel 5: context[b][d] = sum_t w[b][t] * feat[b][t][d]
// grid (64, 8); 256 threads = 16 d-quads (float4) x 16 t-subgroups.
// ---------------------------------------------------------------------------
__global__ void k_context(const float* __restrict__ feat, float* __restrict__ dout) {
    const int b = blockIdx.x, dc = blockIdx.y;
    const int dq = threadIdx.x & 15;          // float4 lane
    const int ty = threadIdx.x >> 4;          // 0..15
    const int d = dc * 64 + dq * 4;
    const float* wgt = dout + ATTN_OFF + (size_t)b * TT;
    const float* f = feat + (size_t)b * TT * DD + d;
    float4 acc = {0.f, 0.f, 0.f, 0.f};
    #pragma unroll 4
    for (int i = 0; i < TT / 16; ++i) {
        int t = i * 16 + ty;
        float wv = wgt[t];
        float4 fv = *(const float4*)(f + (size_t)t * DD);
        acc.x += wv * fv.x; acc.y += wv * fv.y;
        acc.z += wv * fv.z; acc.w += wv * fv.w;
    }
    __shared__ float4 red[16][16];
    red[ty][dq] = acc; __syncthreads();
    if (ty == 0) {
        float4 s = red[0][dq];
        #pragma unroll
        for (int k = 1; k < 16; ++k) {
            float4 r = red[k][dq];
            s.x += r.x; s.y += r.y; s.z += r.z; s.w += r.w;
        }
        *(float4*)(dout + (size_t)b * DD + d) = s;
    }
}

// ---------------------------------------------------------------------------
extern "C" void kernel_launch(void* const* d_in, const int* in_sizes, int n_in,
                              void* d_out, int out_size, void* d_ws, size_t ws_size,
                              hipStream_t stream) {
    (void)in_sizes; (void)n_in; (void)out_size; (void)ws_size;
    const float* feat   = (const float*)d_in[0];
    const float* hidden = (const float*)d_in[1];
    const float* W1     = (const float*)d_in[2];
    const float* b1     = (const float*)d_in[3];
    const float* W2     = (const float*)d_in[4];
    const float* b2     = (const float*)d_in[5];
    const float* V      = (const float*)d_in[6];
    // d_in[7] = bV : softmax-invariant constant, unused.

    // ws layout: [0,512K) W1T bf16; [512K,640K) phc f32; [640K,640K+2M) partials
    unsigned short* W1T = (unsigned short*)d_ws;
    float* phc  = (float*)((char*)d_ws + 512 * 1024);
    float* part = (float*)((char*)d_ws + 640 * 1024);
    float* out  = (float*)d_out;

    hipLaunchKernelGGL(k_w1t,     dim3(128),    dim3(256), 0, stream, W1, W1T);
    hipLaunchKernelGGL(k_phc,     dim3(64),     dim3(512), 0, stream, hidden, W2, b1, b2, phc);
    hipLaunchKernelGGL(k_score,   dim3(256),    dim3(512), 0, stream, feat, W1T, phc, V, part);
    hipLaunchKernelGGL(k_softmax, dim3(64),     dim3(256), 0, stream, part, out);
    hipLaunchKernelGGL(k_context, dim3(64, 8),  dim3(256), 0, stream, feat, out);
}

// Round 7
// 225.930 us; speedup vs baseline: 1.9489x; 1.4460x over previous
//
#include <hip/hip_runtime.h>
#include <hip/hip_bf16.h>

// Problem constants (B=64, T=2048, D=512, U=512)
#define BB 64
#define TT 2048
#define DD 512
#define UU 512
#define MM (BB * TT)                 // 131072 rows
#define CTX_ELEMS (BB * DD)          // context region of d_out
#define ATTN_OFF  CTX_ELEMS          // attention region offset in d_out

typedef __bf16 bf16x8 __attribute__((ext_vector_type(8)));
typedef float  f32x4  __attribute__((ext_vector_type(4)));
typedef unsigned short u16x8 __attribute__((ext_vector_type(8)));
typedef unsigned int u32;

#define GLOBAL_AS __attribute__((address_space(1)))
#define LDS_AS    __attribute__((address_space(3)))

__device__ __forceinline__ unsigned short f2bf(float f) {
    union { float f; unsigned u; } x; x.f = f;
    unsigned r = x.u + 0x7fffu + ((x.u >> 16) & 1u);   // RNE
    return (unsigned short)(r >> 16);
}

__device__ __forceinline__ float tanh_fast(float x) {
    x = fminf(fmaxf(x, -10.f), 10.f);                  // avoid inf*0
    float e = __builtin_amdgcn_exp2f(x * 2.885390082f); // e^(2x)
    return (e - 1.0f) * __builtin_amdgcn_rcpf(e + 1.0f);
}

// ---------------------------------------------------------------------------
// Kernel 1: W1 [D][U] f32 -> W1T bf16, layout:
//   byte offset = ((gy*8 + ktile)*8 + kc)*2048 + n*16
//   gy = u>>7, n = u&127, ktile = d>>6, kc = (d&63)>>3, e = d&7
// Per (gy,ktile): contiguous 16 KB slab [kc(8)][n(128)][8e] -> linear staging.
// ---------------------------------------------------------------------------
__global__ void k_w1t(const float* __restrict__ W1, unsigned short* __restrict__ W1T) {
    int gid = blockIdx.x * 256 + threadIdx.x;   // 32768 threads
    int u  = gid & 511;
    int dc = gid >> 9;                          // d-chunk of 8, 0..63
    int d0 = dc * 8;
    u16x8 pk;
    #pragma unroll
    for (int e = 0; e < 8; ++e)
        pk[e] = f2bf(W1[(size_t)(d0 + e) * UU + u]);
    int gy = u >> 7, n = u & 127;
    int kt = dc >> 3, kc = dc & 7;
    size_t off = (((size_t)(gy * 8 + kt) * 8 + kc) * 1024 + n * 8);  // ushort idx
    *(u16x8*)(W1T + off) = pk;
}

// ---------------------------------------------------------------------------
// Kernel 2: phc[b][u] = b1[u] + b2[u] + hidden[b,:] @ W2[:,u]
// ---------------------------------------------------------------------------
__global__ void k_phc(const float* __restrict__ hidden, const float* __restrict__ W2,
                      const float* __restrict__ b1, const float* __restrict__ b2,
                      float* __restrict__ phc) {
    const int b = blockIdx.x;
    const int u = threadIdx.x;         // 512 threads
    const float* h = hidden + (size_t)b * DD;
    float acc = b1[u] + b2[u];
    #pragma unroll 8
    for (int d = 0; d < DD; ++d)
        acc += h[d] * W2[(size_t)d * UU + u];
    phc[(size_t)b * UU + u] = acc;
}

// ---------------------------------------------------------------------------
// Kernel 3: partial-score GEMM, phase-structured (T3+T4+T5).
// BM=256 x BN=128 x BK=64, 512 threads = 8 waves (4M x 2N). LDS: A dbuf
// 2x32KB [kc8][row256][8e] bf16 (XOR kc*16 swizzle), B dbuf 2x16KB
// [kc8][n128][8e]. K = 8 tiles x 2 phases each; per phase: frag reads ||
// stage-issue (4 A f32 loads + 1 B gload_lds) -> counted vmcnt(5/1) ->
// (p1: cvt+4 ds_write A) -> lgkm0 -> ONE barrier -> setprio+16 MFMA.
// Loads get ~1.5-phase latency window; vmcnt never 0 until the tail.
// Grid 2048 = 512 mt x 4 gy; XCD-grouped so gy-siblings share an XCD.
// ---------------------------------------------------------------------------
__launch_bounds__(512, 1)
__global__ void k_score(const float* __restrict__ feat,
                        const unsigned short* __restrict__ W1T,
                        const float* __restrict__ phc,
                        const float* __restrict__ V,
                        float* __restrict__ part) {
    __shared__ __align__(16) unsigned short sA[2 * 8 * 256 * 8];  // 64 KB
    __shared__ __align__(16) unsigned short sB[2 * 8 * 128 * 8];  // 32 KB
    __shared__ float sRed[8][64];

    const int tid  = threadIdx.x;
    const int lane = tid & 63;
    const int w    = tid >> 6;                 // wave 0..7
    const int wm   = w >> 1, wc = w & 1;       // 4M x 2N

    const int bid = blockIdx.x;
    const int xcd = bid & 7;
    const int idx = bid >> 3;
    const int gy  = idx & 3;
    const int mt  = xcd * 64 + (idx >> 2);     // 0..511
    const int m0  = mt * 256;
    const int b   = m0 >> 11;

    const int kcl   = lane >> 4;               // 0..3
    const int rlane = lane & 15;

    // A f32 source: thread covers row (tid>>3) of each 64-row round, k-chunk (tid&7)*8
    const char* fsrc = (const char*)feat +
        (((size_t)(m0 + (tid >> 3)) * 512) + (size_t)(tid & 7) * 8) * 4;
    // B source slab for this gy
    const char* bsl = (const char*)W1T + (size_t)gy * 8 * 16384;

    // per-block epilogue constants
    float pc[4], vv[4];
    #pragma unroll
    for (int ns = 0; ns < 4; ++ns) {
        int ug = gy * 128 + wc * 64 + ns * 16 + rlane;
        pc[ns] = phc[(size_t)b * UU + ug];
        vv[ns] = V[ug];
    }

    f32x4 rA[8];
    f32x4 acc[4][4];
    #pragma unroll
    for (int i = 0; i < 4; ++i)
        #pragma unroll
        for (int j = 0; j < 4; ++j)
            acc[i][j] = (f32x4){0.f, 0.f, 0.f, 0.f};

#define VMW(N)  asm volatile("s_waitcnt vmcnt(" #N ")" ::: "memory")
#define LGKM0() asm volatile("s_waitcnt lgkmcnt(0)" ::: "memory")

    // issue A-round pair for tile tt, phase p -> rA[4p..4p+3]
#define ISSUE_A(tt_, p_) do {                                                    \
    rA[4*(p_)+0] = *(const f32x4*)(fsrc + (size_t)(2*(p_))  *131072 + (tt_)*256);     \
    rA[4*(p_)+1] = *(const f32x4*)(fsrc + (size_t)(2*(p_))  *131072 + (tt_)*256 + 16);\
    rA[4*(p_)+2] = *(const f32x4*)(fsrc + (size_t)(2*(p_)+1)*131072 + (tt_)*256);     \
    rA[4*(p_)+3] = *(const f32x4*)(fsrc + (size_t)(2*(p_)+1)*131072 + (tt_)*256 + 16);\
    } while (0)

#define ISSUE_B(tt_, p_) do {                                                    \
    const char* src_ = bsl + (size_t)(tt_) * 16384 + (p_) * 8192 + tid * 16;     \
    char* dst_ = (char*)sB + ((tt_) & 1) * 16384 + (p_) * 8192 + (tid & ~63) * 16;\
    __builtin_amdgcn_global_load_lds((const GLOBAL_AS u32*)src_,                 \
                                     (LDS_AS u32*)dst_, 16, 0, 0); } while (0)

    // cvt rA -> bf16 and write A tile tt (buf tt&1), XOR kc*16 swizzle
#define WRITE_A(tt_) do {                                                        \
    const int kcw_ = tid & 7;                                                    \
    _Pragma("unroll")                                                            \
    for (int j_ = 0; j_ < 4; ++j_) {                                             \
        bf16x8 q_;                                                               \
        _Pragma("unroll")                                                        \
        for (int e_ = 0; e_ < 4; ++e_) {                                         \
            q_[e_]     = (__bf16)rA[2*j_][e_];                                   \
            q_[4 + e_] = (__bf16)rA[2*j_ + 1][e_];                               \
        }                                                                        \
        int row_ = j_ * 64 + (tid >> 3);                                         \
        int byt_ = ((tt_) & 1) * 32768 + kcw_ * 4096 + ((row_ * 16) ^ (kcw_ * 16));\
        *(bf16x8*)((char*)sA + byt_) = q_;                                       \
    } } while (0)

    // One phase. PRE: 1 = stage tile t+1. VM: 0=vmcnt(5), 1=vmcnt(1),
    // 2=vmcnt(0), 3=no wait.
#define PH(t_, p_, PRE_, VM_) do {                                               \
    bf16x8 af[4], bfr[4];                                                        \
    _Pragma("unroll")                                                            \
    for (int ms_ = 0; ms_ < 4; ++ms_) {                                          \
        int kc_ = (p_) * 4 + kcl;                                                \
        int row_ = wm * 64 + ms_ * 16 + rlane;                                   \
        af[ms_] = *(const bf16x8*)((const char*)sA + ((t_) & 1) * 32768 +        \
                   kc_ * 4096 + ((row_ * 16) ^ (kc_ * 16)));                     \
    }                                                                            \
    _Pragma("unroll")                                                            \
    for (int ns_ = 0; ns_ < 4; ++ns_) {                                          \
        int kc_ = (p_) * 4 + kcl;                                                \
        bfr[ns_] = *(const bf16x8*)((const char*)sB + ((t_) & 1) * 16384 +       \
                    kc_ * 2048 + (wc * 64 + ns_ * 16 + rlane) * 16);             \
    }                                                                            \
    if (PRE_) { ISSUE_A((t_) + 1, p_); ISSUE_B((t_) + 1, p_); }                  \
    if ((VM_) == 0) VMW(5); else if ((VM_) == 1) VMW(1); else if ((VM_) == 2) VMW(0); \
    if ((p_) == 1 && (PRE_)) WRITE_A((t_) + 1);                                  \
    LGKM0();                                                                     \
    __builtin_amdgcn_s_barrier();                                                \
    __builtin_amdgcn_sched_barrier(0);                                           \
    __builtin_amdgcn_s_setprio(1);                                               \
    _Pragma("unroll")                                                            \
    for (int ms_ = 0; ms_ < 4; ++ms_)                                            \
        _Pragma("unroll")                                                        \
        for (int ns_ = 0; ns_ < 4; ++ns_)                                        \
            acc[ms_][ns_] = __builtin_amdgcn_mfma_f32_16x16x32_bf16(             \
                af[ms_], bfr[ns_], acc[ms_][ns_], 0, 0, 0);                      \
    __builtin_amdgcn_s_setprio(0); } while (0)

    // ---- prologue: stage tile 0 fully ----
    ISSUE_A(0, 0);   // rA[0..3]
    ISSUE_A(0, 1);   // rA[4..7]
    ISSUE_B(0, 0);
    ISSUE_B(0, 1);
    VMW(1);          // retire A(0)x8 + B(0,klo); keep B(0,khi) in flight
    WRITE_A(0);
    LGKM0();
    __builtin_amdgcn_s_barrier();

    // ---- 8 K-tiles x 2 phases; steady vmcnt(5)/vmcnt(1) ----
    PH(0, 0, 1, 0); PH(0, 1, 1, 1);
    PH(1, 0, 1, 0); PH(1, 1, 1, 1);
    PH(2, 0, 1, 0); PH(2, 1, 1, 1);
    PH(3, 0, 1, 0); PH(3, 1, 1, 1);
    PH(4, 0, 1, 0); PH(4, 1, 1, 1);
    PH(5, 0, 1, 0); PH(5, 1, 1, 1);
    PH(6, 0, 1, 0); PH(6, 1, 1, 1);
    PH(7, 0, 0, 2); PH(7, 1, 0, 3);   // tail: drain B(7,khi), then compute-only

#undef PH
#undef WRITE_A
#undef ISSUE_B
#undef ISSUE_A
#undef VMW
#undef LGKM0

    // --- epilogue: partial score over this block's 128 n-cols ---
    float pr[4][4];
    #pragma unroll
    for (int ms = 0; ms < 4; ++ms)
        #pragma unroll
        for (int rg = 0; rg < 4; ++rg) {
            float s = 0.f;
            #pragma unroll
            for (int ns = 0; ns < 4; ++ns)
                s += tanh_fast(acc[ms][ns][rg] + pc[ns]) * vv[ns];
            pr[ms][rg] = s;
        }
    #pragma unroll
    for (int off = 1; off < 16; off <<= 1)
        #pragma unroll
        for (int ms = 0; ms < 4; ++ms)
            #pragma unroll
            for (int rg = 0; rg < 4; ++rg)
                pr[ms][rg] += __shfl_xor(pr[ms][rg], off, 64);
    __syncthreads();   // K-loop LDS reads fully done before sRed reuse is moot (separate buf), but cheap
    if ((lane & 15) == 0) {
        int rowg = lane >> 4;
        #pragma unroll
        for (int ms = 0; ms < 4; ++ms)
            #pragma unroll
            for (int rg = 0; rg < 4; ++rg)
                sRed[w][ms * 16 + rowg * 4 + rg] = pr[ms][rg];
    }
    __syncthreads();
    if (tid < 256) {
        int wmx = tid >> 6, r = tid & 63;
        float v = sRed[2 * wmx][r] + sRed[2 * wmx + 1][r];
        part[(size_t)gy * MM + m0 + tid] = v;
    }
}

// ---------------------------------------------------------------------------
// Kernel 4: sum 4 partials -> softmax over T -> d_out attn region.
// ---------------------------------------------------------------------------
__global__ void k_softmax(const float* __restrict__ part, float* __restrict__ dout) {
    const int b = blockIdx.x, tid = threadIdx.x;   // 256 threads
    float* sc = dout + ATTN_OFF + (size_t)b * TT;
    float v[8];
    float mx = -3.4e38f;
    #pragma unroll
    for (int i = 0; i < 8; ++i) {
        int t = tid + 256 * i;
        size_t idx = (size_t)b * TT + t;
        v[i] = part[idx] + part[MM + idx] + part[2 * MM + idx] + part[3 * MM + idx];
        mx = fmaxf(mx, v[i]);
    }
    __shared__ float red[256];
    red[tid] = mx; __syncthreads();
    for (int s = 128; s >= 1; s >>= 1) {
        if (tid < s) red[tid] = fmaxf(red[tid], red[tid + s]);
        __syncthreads();
    }
    mx = red[0]; __syncthreads();
    float sum = 0.f;
    #pragma unroll
    for (int i = 0; i < 8; ++i) { v[i] = __expf(v[i] - mx); sum += v[i]; }
    red[tid] = sum; __syncthreads();
    for (int s = 128; s >= 1; s >>= 1) {
        if (tid < s) red[tid] += red[tid + s];
        __syncthreads();
    }
    float inv = 1.0f / red[0];
    #pragma unroll
    for (int i = 0; i < 8; ++i) sc[tid + 256 * i] = v[i] * inv;
}

// ---------------------------------------------------------------------------
// Kernel 5: context[b][d] = sum_t w[b][t] * feat[b][t][d]
// grid (64, 8); 256 threads = 16 d-quads (float4) x 16 t-subgroups.
// ---------------------------------------------------------------------------
__global__ void k_context(const float* __restrict__ feat, float* __restrict__ dout) {
    const int b = blockIdx.x, dc = blockIdx.y;
    const int dq = threadIdx.x & 15;          // float4 lane
    const int ty = threadIdx.x >> 4;          // 0..15
    const int d = dc * 64 + dq * 4;
    const float* wgt = dout + ATTN_OFF + (size_t)b * TT;
    const float* f = feat + (size_t)b * TT * DD + d;
    float4 acc = {0.f, 0.f, 0.f, 0.f};
    #pragma unroll 4
    for (int i = 0; i < TT / 16; ++i) {
        int t = i * 16 + ty;
        float wv = wgt[t];
        float4 fv = *(const float4*)(f + (size_t)t * DD);
        acc.x += wv * fv.x; acc.y += wv * fv.y;
        acc.z += wv * fv.z; acc.w += wv * fv.w;
    }
    __shared__ float4 red[16][16];
    red[ty][dq] = acc; __syncthreads();
    if (ty == 0) {
        float4 s = red[0][dq];
        #pragma unroll
        for (int k = 1; k < 16; ++k) {
            float4 r = red[k][dq];
            s.x += r.x; s.y += r.y; s.z += r.z; s.w += r.w;
        }
        *(float4*)(dout + (size_t)b * DD + d) = s;
    }
}

// ---------------------------------------------------------------------------
extern "C" void kernel_launch(void* const* d_in, const int* in_sizes, int n_in,
                              void* d_out, int out_size, void* d_ws, size_t ws_size,
                              hipStream_t stream) {
    (void)in_sizes; (void)n_in; (void)out_size; (void)ws_size;
    const float* feat   = (const float*)d_in[0];
    const float* hidden = (const float*)d_in[1];
    const float* W1     = (const float*)d_in[2];
    const float* b1     = (const float*)d_in[3];
    const float* W2     = (const float*)d_in[4];
    const float* b2     = (const float*)d_in[5];
    const float* V      = (const float*)d_in[6];
    // d_in[7] = bV : softmax-invariant constant, unused.

    // ws layout: [0,512K) W1T bf16; [512K,640K) phc f32; [640K,640K+2M) partials
    unsigned short* W1T = (unsigned short*)d_ws;
    float* phc  = (float*)((char*)d_ws + 512 * 1024);
    float* part = (float*)((char*)d_ws + 640 * 1024);
    float* out  = (float*)d_out;

    hipLaunchKernelGGL(k_w1t,     dim3(128),    dim3(256), 0, stream, W1, W1T);
    hipLaunchKernelGGL(k_phc,     dim3(64),     dim3(512), 0, stream, hidden, W2, b1, b2, phc);
    hipLaunchKernelGGL(k_score,   dim3(2048),   dim3(512), 0, stream, feat, W1T, phc, V, part);
    hipLaunchKernelGGL(k_softmax, dim3(64),     dim3(256), 0, stream, part, out);
    hipLaunchKernelGGL(k_context, dim3(64, 8),  dim3(256), 0, stream, feat, out);
}